// Round 1
// baseline (332.078 us; speedup 1.0000x reference)
//
#include <hip/hip_runtime.h>

// BSplines: elementwise cubic de Boor evaluation, memory-bound streaming.
// t (9 knots) and c (5 coeffs) are uniform -> scalar loads; the interval
// index m is only ever 3 or 4 (clip(searchsorted-1, 3, 4) with the fixed
// clamped-knot layout), so all knot lookups become 2-way selects on
// up = (x >= t[4]). Reciprocals of the 12 possible denominators are
// precomputed per thread (loop-invariant, hoisted out of the grid-stride
// loop) so the per-element path is pure VALU: ~45 ops/element.

__global__ __launch_bounds__(256) void bspline_kernel(
    const float4* __restrict__ in4,
    float4* __restrict__ out4,
    const float* __restrict__ t,
    const float* __restrict__ c,
    int n4)
{
    // Uniform loads (compiler emits scalar loads: uniform ptr + const offset)
    const float t1 = t[1], t2 = t[2], t3 = t[3], t4 = t[4],
                t5 = t[5], t6 = t[6], t7 = t[7];
    const float c0 = c[0], c1 = c[1], c2 = c[2], c3 = c[3], c4 = c[4];

    // rd = denom > 0 ? 1/denom : 0  (exact division; once per thread)
    auto rdf = [](float lo, float hi) -> float {
        float d = hi - lo;
        return d > 0.f ? 1.f / d : 0.f;
    };

    // (r,j) pairs of the de Boor recursion; left = t[j+m-3], right = t[j+1+m-r]
    // suffix _3 = (m==3), _4 = (m==4)
    const float L13_3 = t3, L13_4 = t4, RD13_3 = rdf(t3, t6), RD13_4 = rdf(t4, t7);
    const float L12_3 = t2, L12_4 = t3, RD12_3 = rdf(t2, t5), RD12_4 = rdf(t3, t6);
    const float L11_3 = t1, L11_4 = t2, RD11_3 = rdf(t1, t4), RD11_4 = rdf(t2, t5);
    const float L23_3 = t3, L23_4 = t4, RD23_3 = rdf(t3, t5), RD23_4 = rdf(t4, t6);
    const float L22_3 = t2, L22_4 = t3, RD22_3 = rdf(t2, t4), RD22_4 = rdf(t3, t5);
    const float L33_3 = t3, L33_4 = t4, RD33_3 = rdf(t3, t4), RD33_4 = rdf(t4, t5);

    auto eval = [&](float x) -> float {
        // m = clip(searchsorted(t,x,'right')-1, 3, 4); with sorted t this is
        // exactly: m==4  <=>  t[4] <= x
        const bool up = (x >= t4);
        float d0 = up ? c1 : c0;
        float d1 = up ? c2 : c1;
        float d2 = up ? c3 : c2;
        float d3 = up ? c4 : c3;
        float a;
        // r = 1 (j = 3,2,1)
        a = (x - (up ? L13_4 : L13_3)) * (up ? RD13_4 : RD13_3);
        d3 = fmaf(a, d3 - d2, d2);
        a = (x - (up ? L12_4 : L12_3)) * (up ? RD12_4 : RD12_3);
        d2 = fmaf(a, d2 - d1, d1);
        a = (x - (up ? L11_4 : L11_3)) * (up ? RD11_4 : RD11_3);
        d1 = fmaf(a, d1 - d0, d0);
        // r = 2 (j = 3,2)
        a = (x - (up ? L23_4 : L23_3)) * (up ? RD23_4 : RD23_3);
        d3 = fmaf(a, d3 - d2, d2);
        a = (x - (up ? L22_4 : L22_3)) * (up ? RD22_4 : RD22_3);
        d2 = fmaf(a, d2 - d1, d1);
        // r = 3 (j = 3)
        a = (x - (up ? L33_4 : L33_3)) * (up ? RD33_4 : RD33_3);
        d3 = fmaf(a, d3 - d2, d2);
        // zero-mask where input was exactly zero
        return (x == 0.f) ? 0.f : d3;
    };

    const int stride = gridDim.x * blockDim.x;
    for (int i = blockIdx.x * blockDim.x + threadIdx.x; i < n4; i += stride) {
        float4 v = in4[i];
        float4 o;
        o.x = eval(v.x);
        o.y = eval(v.y);
        o.z = eval(v.z);
        o.w = eval(v.w);
        out4[i] = o;
    }
}

extern "C" void kernel_launch(void* const* d_in, const int* in_sizes, int n_in,
                              void* d_out, int out_size, void* d_ws, size_t ws_size,
                              hipStream_t stream) {
    const float* imgs = (const float*)d_in[0];
    const float* t    = (const float*)d_in[1];
    const float* c    = (const float*)d_in[2];
    float* out = (float*)d_out;

    const int n  = in_sizes[0];      // 64*3*512*512 = 50331648, divisible by 4
    const int n4 = n / 4;            // 12582912 float4s

    const int block = 256;
    // grid-stride: 2M threads -> 6 iterations each; amortizes the per-thread
    // knot/reciprocal precompute to ~5% while keeping 32 waves/CU in flight
    int grid = 8192;
    int max_grid = (n4 + block - 1) / block;
    if (grid > max_grid) grid = max_grid;

    bspline_kernel<<<grid, block, 0, stream>>>(
        (const float4*)imgs, (float4*)out, t, c, n4);
}

// Round 2
// 319.193 us; speedup vs baseline: 1.0404x; 1.0404x over previous
//
#include <hip/hip_runtime.h>

// BSplines: elementwise cubic B-spline, memory-bound streaming.
//
// Key structural facts exploited:
//  - knot layout t = [0,0,0,0, 0.5, 1,1,1,1]: the clipped interval index m is
//    only ever 3 or 4, i.e. the whole spline is TWO cubic polynomials split
//    at t[4].
//  - de Boor is expanded SYMBOLICALLY once per thread in the preamble
//    (template-unrolled polynomial arithmetic -> monomial coeffs for each
//    piece, all register-resident). Per-element work is then just:
//    1 cmp + 4 cndmask (pick piece coeffs) + 3 FMA Horner + zero-mask
//    ≈ 10 VALU ops/elem vs ~43 for inline de Boor — removes the VALU/latency
//    bottleneck that held R1 at ~55% of streaming BW.
//  - nontemporal float4 loads/stores: zero reuse, 402 MB stream > 256 MB L3.

typedef float v4f __attribute__((ext_vector_type(4)));

// Expand the de Boor recursion for fixed interval M into monomial
// coefficients out[0..3] (out[0] + out[1]x + out[2]x^2 + out[3]x^3).
// All loops unroll fully; all array indices are compile-time constants,
// so P[][] stays in registers.
template<int M>
__device__ inline void expand_piece(const float tt[9], const float cc[5],
                                    float out[4]) {
    float P[4][4];
#pragma unroll
    for (int j = 0; j < 4; ++j) {
        P[j][0] = cc[M - 3 + j];
        P[j][1] = 0.f; P[j][2] = 0.f; P[j][3] = 0.f;
    }
#pragma unroll
    for (int r = 1; r <= 3; ++r) {
#pragma unroll
        for (int j = 3; j >= 1; --j) {
            if (j < r) continue;
            const float L   = tt[j + M - 3];
            const float R   = tt[j + 1 + M - r];
            const float den = R - L;
            const float rd  = den > 0.f ? 1.f / den : 0.f;
            // alpha(x) = rd*x - rd*L  -> linear (p x + q)
            const float p = rd;
            const float q = -rd * L;
            // e = P[j] - P[j-1];  P[j] = P[j-1] + (p x + q) * e
            const float e0 = P[j][0] - P[j-1][0];
            const float e1 = P[j][1] - P[j-1][1];
            const float e2 = P[j][2] - P[j-1][2];
            const float e3 = P[j][3] - P[j-1][3];
            P[j][0] = P[j-1][0] + q * e0;
            P[j][1] = P[j-1][1] + q * e1 + p * e0;
            P[j][2] = P[j-1][2] + q * e2 + p * e1;
            P[j][3] = P[j-1][3] + q * e3 + p * e2;
        }
    }
#pragma unroll
    for (int i = 0; i < 4; ++i) out[i] = P[3][i];
}

__global__ __launch_bounds__(256) void bspline_kernel(
    const v4f* __restrict__ in4,
    v4f* __restrict__ out4,
    const float* __restrict__ t,
    const float* __restrict__ c,
    int n4)
{
    // Uniform preamble (once per thread, overlapped with first loads):
    float tt[9], cc[5];
#pragma unroll
    for (int i = 0; i < 9; ++i) tt[i] = t[i];
#pragma unroll
    for (int i = 0; i < 5; ++i) cc[i] = c[i];

    float A[4], B[4];               // piece polys: A for m=3 (x < t4), B for m=4
    expand_piece<3>(tt, cc, A);
    expand_piece<4>(tt, cc, B);
    const float t4 = tt[4];

    auto eval = [&](float x) -> float {
        const bool up = (x >= t4);
        const float k0 = up ? B[0] : A[0];
        const float k1 = up ? B[1] : A[1];
        const float k2 = up ? B[2] : A[2];
        const float k3 = up ? B[3] : A[3];
        float y = fmaf(fmaf(fmaf(k3, x, k2), x, k1), x, k0);
        return (x == 0.f) ? 0.f : y;
    };

    const int tid    = blockIdx.x * (blockDim.x * 2) + threadIdx.x;
    const int stride = gridDim.x * blockDim.x * 2;

    for (int i0 = tid; i0 < n4; i0 += stride) {
        const int i1 = i0 + blockDim.x;
        v4f v0 = __builtin_nontemporal_load(&in4[i0]);
        v4f v1;
        const bool has1 = (i1 < n4);
        if (has1) v1 = __builtin_nontemporal_load(&in4[i1]);

        v4f o0, o1;
        o0.x = eval(v0.x); o0.y = eval(v0.y);
        o0.z = eval(v0.z); o0.w = eval(v0.w);
        __builtin_nontemporal_store(o0, &out4[i0]);

        if (has1) {
            o1.x = eval(v1.x); o1.y = eval(v1.y);
            o1.z = eval(v1.z); o1.w = eval(v1.w);
            __builtin_nontemporal_store(o1, &out4[i1]);
        }
    }
}

extern "C" void kernel_launch(void* const* d_in, const int* in_sizes, int n_in,
                              void* d_out, int out_size, void* d_ws, size_t ws_size,
                              hipStream_t stream) {
    const float* imgs = (const float*)d_in[0];
    const float* t    = (const float*)d_in[1];
    const float* c    = (const float*)d_in[2];
    float* out = (float*)d_out;

    const int n  = in_sizes[0];      // 64*3*512*512 = 50331648 (divisible by 4)
    const int n4 = n / 4;            // 12582912 float4s

    const int block = 256;
    // 8192 blocks * 256 thr * 2 unroll = 4 Mi float4 per sweep -> exactly 3
    // grid-stride iterations; 32768 waves = 4x CU oversubscription, preamble
    // (poly expansion) amortized over 6 float4s/thread.
    int grid = 8192;
    int max_grid = (n4 + block * 2 - 1) / (block * 2);
    if (grid > max_grid) grid = max_grid;

    bspline_kernel<<<grid, block, 0, stream>>>(
        (const v4f*)imgs, (v4f*)out, t, c, n4);
}